// Round 2
// baseline (352.678 us; speedup 1.0000x reference)
//
#include <hip/hip_runtime.h>
#include <stdint.h>

#pragma clang fp contract(off)

#define NCELL 49
#define NCLS  20
#define DDIM  30

struct Box { float x1, y1, x2, y2; };

__device__ __forceinline__ float sigmoid_ref(float x) {
#pragma clang fp contract(off)
  if (x >= 0.0f) {
    float z = expf(-x);
    return 1.0f / (1.0f + z);
  } else {
    float z = expf(x);
    return z / (1.0f + z);
  }
}

__device__ __forceinline__ float iou_box(Box a, Box b) {
#pragma clang fp contract(off)
  float lx = fmaxf(a.x1, b.x1);
  float ly = fmaxf(a.y1, b.y1);
  float rx = fminf(a.x2, b.x2);
  float ry = fminf(a.y2, b.y2);
  float w = fmaxf(rx - lx, 0.0f);
  float h = fmaxf(ry - ly, 0.0f);
  float inter = w * h;
  float aa = (a.x2 - a.x1) * (a.y2 - a.y1);
  float ab = (b.x2 - b.x1) * (b.y2 - b.y1);
  return inter / (aa + ab - inter);
}

__global__ __launch_bounds__(64) void k_per_image(
    const float* __restrict__ target, const float* __restrict__ output,
    uint8_t* __restrict__ entries, int* __restrict__ gt_count, int batch)
{
#pragma clang fp contract(off)
  int img = blockIdx.x;
  if (img >= batch) return;
  int lane = threadIdx.x;
  const float* T = target + (size_t)img * (NCELL * DDIM);
  const float* O = output + (size_t)img * (NCELL * DDIM);

  __shared__ float   pc[NCELL];   // pre-sort pred conf
  __shared__ Box     pb[NCELL];   // pre-sort pred box
  __shared__ int     pk[NCELL];   // pre-sort pred class
  __shared__ float   sc[NCELL];   // sorted conf
  __shared__ Box     sb[NCELL];
  __shared__ int     sk[NCELL];
  __shared__ Box     gb[NCELL];   // GT boxes
  __shared__ int     gk[NCELL];   // GT class
  __shared__ uint8_t gv[NCELL];   // GT valid
  __shared__ uint8_t sup[NCELL];  // NMS suppressed
  __shared__ uint8_t vp[NCELL];   // valid pred
  __shared__ float   mxs[NCELL];  // best IoU vs GT
  __shared__ uint8_t bests[NCELL];
  __shared__ uint8_t tps[NCELL];
  __shared__ int     cnt[NCLS];

  if (lane < NCLS) cnt[lane] = 0;

  if (lane < NCELL) {
    int iy = lane / 7, jx = lane % 7;
    float fjx = (float)jx, fiy = (float)iy;

    // ---- ground truth (raw target, no sigmoid) ----
    float tv[DDIM];
#pragma unroll
    for (int i = 0; i < DDIM; ++i) tv[i] = T[lane * DDIM + i];
    float tconf = tv[4];
    int tcls = 0; float tbv = tv[10];
#pragma unroll
    for (int c = 1; c < NCLS; ++c) { float v = tv[10 + c]; if (v > tbv) { tbv = v; tcls = c; } }
    {
      float cx = (tv[0] + fjx) * 64.0f;
      float cy = (tv[1] + fiy) * 64.0f;
      float w  = tv[2] * 448.0f;
      float h  = tv[3] * 448.0f;
      Box g;
      g.x1 = cx - w * 0.5f;  // w/2 == w*0.5 exactly in fp32
      g.y1 = cy - h * 0.5f;
      g.x2 = cx + w * 0.5f;
      g.y2 = cy + h * 0.5f;
      gb[lane] = g; gk[lane] = tcls;
      gv[lane] = (tconf > 0.5f) ? 1 : 0;
    }

    // ---- prediction (sigmoid everything) ----
    float ov[DDIM];
#pragma unroll
    for (int i = 0; i < DDIM; ++i) ov[i] = sigmoid_ref(O[lane * DDIM + i]);
    float c0 = ov[4], c1 = ov[9];
    float oc = fmaxf(c0, c1);
    int resp = (c1 > c0) ? 1 : 0;     // argmax, first max wins
    float x = ov[resp * 5 + 0], y = ov[resp * 5 + 1];
    float w = ov[resp * 5 + 2], h = ov[resp * 5 + 3];
    int ocls = 0; float obv = ov[10];
#pragma unroll
    for (int c = 1; c < NCLS; ++c) { float v = ov[10 + c]; if (v > obv) { obv = v; ocls = c; } }
    {
      float cx = (x + fjx) * 64.0f;
      float cy = (y + fiy) * 64.0f;
      float W  = w * 448.0f;
      float H  = h * 448.0f;
      Box p;
      p.x1 = cx - W * 0.5f;
      p.y1 = cy - H * 0.5f;
      p.x2 = cx + W * 0.5f;
      p.y2 = cy + H * 0.5f;
      pb[lane] = p; pc[lane] = oc; pk[lane] = ocls;
    }
  }
  __syncthreads();

  // ---- stable sort by conf desc via rank (matches stable argsort(-oc)) ----
  if (lane < NCELL) {
    if (gv[lane]) atomicAdd(&cnt[gk[lane]], 1);
    float myc = pc[lane];
    int r = 0;
#pragma unroll
    for (int j = 0; j < NCELL; ++j) {
      float cj = pc[j];
      r += (cj > myc) || (cj == myc && j < lane);
    }
    sc[r] = myc; sb[r] = pb[lane]; sk[r] = pk[lane];
    sup[lane] = 0;
  }
  __syncthreads();

  Box myb; int myk = -1; float myc = 0.0f;
  if (lane < NCELL) { myb = sb[lane]; myk = sk[lane]; myc = sc[lane]; }

  // ---- greedy class-aware NMS (sequential over conf-desc order) ----
  for (int i = 0; i < NCELL; ++i) {
    __syncthreads();
    bool act = (sup[i] == 0);
    if (act && lane < NCELL && lane > i && myk == sk[i]) {
      if (iou_box(myb, sb[i]) > 0.5f) sup[lane] = 1;
    }
  }
  __syncthreads();

  // ---- best-matching GT per pred ----
  if (lane < NCELL) {
    float mx = -1.0f; int best = 0;
#pragma unroll 1
    for (int g = 0; g < NCELL; ++g) {
      if (gv[g] && gk[g] == myk) {
        float v = iou_box(myb, gb[g]);
        if (v > mx) { mx = v; best = g; }
      }
    }
    mxs[lane] = mx;
    bests[lane] = (uint8_t)best;
    vp[lane] = (sup[lane] == 0 && myc > 0.5f) ? 1 : 0;
  }
  __syncthreads();

  // ---- greedy TP assignment (serial on lane 0) ----
  if (lane == 0) {
    uint64_t matched = 0;
#pragma unroll 1
    for (int i = 0; i < NCELL; ++i) {
      int b = bests[i];
      bool hit = vp[i] && (mxs[i] > 0.5f) && !((matched >> b) & 1ull);
      if (hit) matched |= (1ull << b);
      tps[i] = hit ? 1 : 0;
    }
  }
  __syncthreads();

  if (lane < NCELL) {
    entries[(size_t)img * NCELL + lane] =
        (uint8_t)(sk[lane] | (vp[lane] << 5) | (tps[lane] << 6));
  }
  if (lane < NCLS && cnt[lane] > 0) atomicAdd(&gt_count[lane], cnt[lane]);
}

// One block per class: segmented scan of the flattened (image-major,
// conf-desc) entry stream. Only TP entries contribute nonzero trapezoid
// terms (Δrecall == 0 exactly elsewhere since cumsums are integer fp32).
__global__ __launch_bounds__(256) void k_ap(
    const uint8_t* __restrict__ entries, const int* __restrict__ gt_count,
    float* __restrict__ ap_out, int ne)
{
#pragma clang fp contract(off)
  int c = blockIdx.x;
  int tid = threadIdx.x;
  int wid = tid >> 6, lid = tid & 63;
  float g2 = (float)gt_count[c] + 1e-6f;

  __shared__ unsigned wtot[4];
  __shared__ double wacc[4];

  unsigned jb = 0, tb = 0;   // running valid-count / tp-count for this class
  double acc = 0.0;
  int ntiles = (ne + 1023) >> 10;

  for (int tile = 0; tile < ntiles; ++tile) {
    int base = (tile << 10) + (tid << 2);
    unsigned wrd = 0;
    if (base + 4 <= ne) {
      wrd = *(const unsigned*)(entries + base);
    } else {
      for (int k = 0; k < 4; ++k)
        if (base + k < ne) wrd |= ((unsigned)entries[base + k]) << (8 * k);
    }
    unsigned val = 0, m4 = 0, t4 = 0;
#pragma unroll
    for (int k = 0; k < 4; ++k) {
      unsigned b = (wrd >> (8 * k)) & 0xffu;
      bool m = (b & 32u) && ((b & 31u) == (unsigned)c);
      if (m) {
        m4 |= 1u << k; val += 0x10000u;
        if (b & 64u) { t4 |= 1u << k; val += 1u; }
      }
    }
    // inclusive wave scan of packed (valid<<16 | tp)
    unsigned incl = val;
#pragma unroll
    for (int d = 1; d < 64; d <<= 1) {
      unsigned n = __shfl_up(incl, d, 64);
      if (lid >= d) incl += n;
    }
    if (lid == 63) wtot[wid] = incl;
    __syncthreads();
    unsigned offs = 0;
    for (int w2 = 0; w2 < wid; ++w2) offs += wtot[w2];
    unsigned excl = incl - val + offs;
    unsigned total = wtot[0] + wtot[1] + wtot[2] + wtot[3];

    unsigned jr = jb + (excl >> 16);
    unsigned tr = tb + (excl & 0xffffu);
#pragma unroll
    for (int k = 0; k < 4; ++k) {
      if (m4 & (1u << k)) {
        jr++;
        if (t4 & (1u << k)) {
          tr++;
          float ft = (float)tr, fj = (float)jr;
          float r_cur  = ft / g2;
          float r_prev = (ft - 1.0f) / g2;
          float p_cur  = ft / (fj + 1e-6f);
          // previous full-array position: prec = (t-1)/((j-1)+1e-6);
          // the prepended p=1 only applies at global position 0.
          float p_prev = ((base + k) == 0) ? 1.0f
                                           : (ft - 1.0f) / ((fj - 1.0f) + 1e-6f);
          float term = (r_cur - r_prev) * (p_cur + p_prev) * 0.5f;
          acc += (double)term;
        }
      }
    }
    jb += total >> 16;
    tb += total & 0xffffu;
    __syncthreads();   // protect wtot before next tile
  }

  // reduce acc across the block
  for (int d = 32; d > 0; d >>= 1) acc += __shfl_down(acc, d, 64);
  if (lid == 0) wacc[wid] = acc;
  __syncthreads();
  if (tid == 0) {
    double s = wacc[0] + wacc[1] + wacc[2] + wacc[3];
    ap_out[c] = (float)s;   // reference rounds per-class AP to fp32
  }
}

__global__ void k_final(const float* __restrict__ ap,
                        const int* __restrict__ gt_count,
                        float* __restrict__ out)
{
#pragma clang fp contract(off)
  if (threadIdx.x == 0 && blockIdx.x == 0) {
    float s = 0.0f, n = 0.0f;
    for (int c = 0; c < NCLS; ++c) {
      if (gt_count[c] > 0) { s += ap[c]; n += 1.0f; }
    }
    float nh = fmaxf(n, 1.0f);
    out[0] = s / nh;
  }
}

extern "C" void kernel_launch(void* const* d_in, const int* in_sizes, int n_in,
                              void* d_out, int out_size, void* d_ws, size_t ws_size,
                              hipStream_t stream) {
  const float* target = (const float*)d_in[0];
  const float* output = (const float*)d_in[1];
  int batch = in_sizes[0] / (NCELL * DDIM);
  int ne = batch * NCELL;

  uint8_t* entries = (uint8_t*)d_ws;
  size_t off = ((size_t)ne + 255) & ~(size_t)255;
  int*   gt_count = (int*)((char*)d_ws + off);
  float* ap       = (float*)((char*)d_ws + off + 64 * sizeof(int));

  (void)hipMemsetAsync(gt_count, 0, 64 * sizeof(int), stream);
  k_per_image<<<batch, 64, 0, stream>>>(target, output, entries, gt_count, batch);
  k_ap<<<NCLS, 256, 0, stream>>>(entries, gt_count, ap, ne);
  k_final<<<1, 64, 0, stream>>>(ap, gt_count, (float*)d_out);
}

// Round 3
// 244.105 us; speedup vs baseline: 1.4448x; 1.4448x over previous
//
#include <hip/hip_runtime.h>
#include <stdint.h>

#pragma clang fp contract(off)

#define NCELL 49
#define NCLS  20
#define DDIM  30

struct Box { float x1, y1, x2, y2; };

__device__ __forceinline__ float sigmoid_ref(float x) {
#pragma clang fp contract(off)
  if (x >= 0.0f) {
    float z = expf(-x);
    return 1.0f / (1.0f + z);
  } else {
    float z = expf(x);
    return z / (1.0f + z);
  }
}

__device__ __forceinline__ float iou_box(Box a, Box b) {
#pragma clang fp contract(off)
  float lx = fmaxf(a.x1, b.x1);
  float ly = fmaxf(a.y1, b.y1);
  float rx = fminf(a.x2, b.x2);
  float ry = fminf(a.y2, b.y2);
  float w = fmaxf(rx - lx, 0.0f);
  float h = fmaxf(ry - ly, 0.0f);
  float inter = w * h;
  float aa = (a.x2 - a.x1) * (a.y2 - a.y1);
  float ab = (b.x2 - b.x1) * (b.y2 - b.y1);
  return inter / (aa + ab - inter);
}

__global__ __launch_bounds__(64) void k_per_image(
    const float* __restrict__ target, const float* __restrict__ output,
    uint8_t* __restrict__ entries, int* __restrict__ gt_count, int batch)
{
#pragma clang fp contract(off)
  int img = blockIdx.x;
  if (img >= batch) return;
  int lane = threadIdx.x;

  __shared__ float2  sT2[NCELL * DDIM / 2];  // 735
  __shared__ float2  sO2[NCELL * DDIM / 2];
  __shared__ float   pc[NCELL];   // pre-sort pred conf
  __shared__ Box     pb[NCELL];   // pre-sort pred box
  __shared__ int     pk[NCELL];   // pre-sort pred class
  __shared__ float   sc[NCELL];   // sorted conf
  __shared__ Box     sb[NCELL];
  __shared__ int     sk[NCELL];
  __shared__ Box     gb[NCELL];   // GT boxes
  __shared__ int     gk[NCELL];   // GT class
  __shared__ uint8_t gv[NCELL];   // GT valid
  __shared__ uint8_t sup[NCELL];  // NMS suppressed
  __shared__ uint8_t vp[NCELL];   // valid pred
  __shared__ float   mxs[NCELL];  // best IoU vs GT
  __shared__ uint8_t bests[NCELL];
  __shared__ uint8_t tps[NCELL];
  __shared__ int     cnt[NCLS];

  if (lane < NCLS) cnt[lane] = 0;

  // coalesced staging: 735 float2 per array
  {
    const float2* T2 = (const float2*)(target + (size_t)img * (NCELL * DDIM));
    const float2* O2 = (const float2*)(output + (size_t)img * (NCELL * DDIM));
    for (int j = lane; j < NCELL * DDIM / 2; j += 64) {
      sT2[j] = T2[j];
      sO2[j] = O2[j];
    }
  }
  __syncthreads();
  const float* sT = (const float*)sT2;
  const float* sO = (const float*)sO2;

  if (lane < NCELL) {
    int iy = lane / 7, jx = lane % 7;
    float fjx = (float)jx, fiy = (float)iy;

    // ---- ground truth (raw target, no sigmoid) ----
    float tv[DDIM];
#pragma unroll
    for (int i = 0; i < DDIM; ++i) tv[i] = sT[lane * DDIM + i];
    float tconf = tv[4];
    int tcls = 0; float tbv = tv[10];
#pragma unroll
    for (int c = 1; c < NCLS; ++c) { float v = tv[10 + c]; if (v > tbv) { tbv = v; tcls = c; } }
    {
      float cx = (tv[0] + fjx) * 64.0f;
      float cy = (tv[1] + fiy) * 64.0f;
      float w  = tv[2] * 448.0f;
      float h  = tv[3] * 448.0f;
      Box g;
      g.x1 = cx - w * 0.5f;
      g.y1 = cy - h * 0.5f;
      g.x2 = cx + w * 0.5f;
      g.y2 = cy + h * 0.5f;
      gb[lane] = g; gk[lane] = tcls;
      gv[lane] = (tconf > 0.5f) ? 1 : 0;
    }

    // ---- prediction (sigmoid everything) ----
    float ov[DDIM];
#pragma unroll
    for (int i = 0; i < DDIM; ++i) ov[i] = sigmoid_ref(sO[lane * DDIM + i]);
    float c0 = ov[4], c1 = ov[9];
    float oc = fmaxf(c0, c1);
    int resp = (c1 > c0) ? 1 : 0;     // argmax, first max wins
    float x = ov[resp * 5 + 0], y = ov[resp * 5 + 1];
    float w = ov[resp * 5 + 2], h = ov[resp * 5 + 3];
    int ocls = 0; float obv = ov[10];
#pragma unroll
    for (int c = 1; c < NCLS; ++c) { float v = ov[10 + c]; if (v > obv) { obv = v; ocls = c; } }
    {
      float cx = (x + fjx) * 64.0f;
      float cy = (y + fiy) * 64.0f;
      float W  = w * 448.0f;
      float H  = h * 448.0f;
      Box p;
      p.x1 = cx - W * 0.5f;
      p.y1 = cy - H * 0.5f;
      p.x2 = cx + W * 0.5f;
      p.y2 = cy + H * 0.5f;
      pb[lane] = p; pc[lane] = oc; pk[lane] = ocls;
    }
  }
  __syncthreads();

  // ---- stable sort by conf desc via rank (matches stable argsort(-oc)) ----
  if (lane < NCELL) {
    if (gv[lane]) atomicAdd(&cnt[gk[lane]], 1);
    float myc = pc[lane];
    int r = 0;
#pragma unroll
    for (int j = 0; j < NCELL; ++j) {
      float cj = pc[j];
      r += (cj > myc) || (cj == myc && j < lane);
    }
    sc[r] = myc; sb[r] = pb[lane]; sk[r] = pk[lane];
    sup[lane] = 0;
  }
  __syncthreads();

  Box myb; int myk = -1; float myc = 0.0f;
  if (lane < NCELL) { myb = sb[lane]; myk = sk[lane]; myc = sc[lane]; }

  // ---- greedy class-aware NMS (sequential over conf-desc order) ----
  for (int i = 0; i < NCELL; ++i) {
    __syncthreads();
    bool act = (sup[i] == 0);
    if (act && lane < NCELL && lane > i && myk == sk[i]) {
      if (iou_box(myb, sb[i]) > 0.5f) sup[lane] = 1;
    }
  }
  __syncthreads();

  // ---- best-matching GT per pred ----
  if (lane < NCELL) {
    float mx = -1.0f; int best = 0;
#pragma unroll 1
    for (int g = 0; g < NCELL; ++g) {
      if (gv[g] && gk[g] == myk) {
        float v = iou_box(myb, gb[g]);
        if (v > mx) { mx = v; best = g; }
      }
    }
    mxs[lane] = mx;
    bests[lane] = (uint8_t)best;
    vp[lane] = (sup[lane] == 0 && myc > 0.5f) ? 1 : 0;
  }
  __syncthreads();

  // ---- greedy TP assignment (serial on lane 0) ----
  if (lane == 0) {
    uint64_t matched = 0;
#pragma unroll 1
    for (int i = 0; i < NCELL; ++i) {
      int b = bests[i];
      bool hit = vp[i] && (mxs[i] > 0.5f) && !((matched >> b) & 1ull);
      if (hit) matched |= (1ull << b);
      tps[i] = hit ? 1 : 0;
    }
  }
  __syncthreads();

  if (lane < NCELL) {
    entries[(size_t)img * NCELL + lane] =
        (uint8_t)(sk[lane] | (vp[lane] << 5) | (tps[lane] << 6));
  }
  if (lane < NCLS && cnt[lane] > 0) atomicAdd(&gt_count[lane], cnt[lane]);
}

// One block per class. Two passes over per-thread CONTIGUOUS segments:
//   pass 1: per-thread (valid, tp) counts -> one 64-bit packed block scan
//   pass 2: re-walk segment with running ranks, emit trapezoid terms.
// Only TP entries contribute (delta-recall == 0 exactly elsewhere).
__global__ __launch_bounds__(256) void k_ap(
    const uint8_t* __restrict__ entries, const int* __restrict__ gt_count,
    float* __restrict__ ap_out, int ne)
{
#pragma clang fp contract(off)
  int c = blockIdx.x;
  int tid = threadIdx.x;
  int wid = tid >> 6, lid = tid & 63;
  float g2 = (float)gt_count[c] + 1e-6f;
  unsigned want = 32u + (unsigned)c;   // valid bit + class field

  int seg = (((ne + 255) >> 8) + 15) & ~15;   // bytes/thread, 16B multiple
  int begin = tid * seg;
  int end = begin + seg; if (end > ne) end = ne;

  // ---- pass 1: count (valid, tp) in my segment ----
  unsigned mv = 0, mt = 0;
  for (int p = begin; p < end; p += 16) {
    if (p + 16 <= ne) {
      uint4 w4 = *(const uint4*)(entries + p);
      unsigned ws[4] = {w4.x, w4.y, w4.z, w4.w};
#pragma unroll
      for (int q = 0; q < 4; ++q) {
        unsigned w = ws[q];
#pragma unroll
        for (int k = 0; k < 4; ++k) {
          unsigned b = (w >> (8 * k)) & 0xffu;
          bool m = (b & 0x3fu) == want;
          if (m) { ++mv; if (b & 64u) ++mt; }
        }
      }
    } else {
      for (int k = 0; p + k < ne && k < 16; ++k) {
        unsigned b = entries[p + k];
        if ((b & 0x3fu) == want) { ++mv; if (b & 64u) ++mt; }
      }
    }
  }

  // ---- 64-bit packed block exclusive scan ----
  unsigned long long packed = ((unsigned long long)mv << 32) | (unsigned long long)mt;
  unsigned long long incl = packed;
#pragma unroll
  for (int d = 1; d < 64; d <<= 1) {
    unsigned long long n = __shfl_up(incl, d, 64);
    if (lid >= d) incl += n;
  }
  __shared__ unsigned long long wtot[4];
  __shared__ double wacc[4];
  if (lid == 63) wtot[wid] = incl;
  __syncthreads();
  unsigned long long offs = 0;
  for (int w2 = 0; w2 < wid; ++w2) offs += wtot[w2];
  unsigned long long excl = incl - packed + offs;
  unsigned jr = (unsigned)(excl >> 32);
  unsigned tr = (unsigned)(excl & 0xffffffffull);

  // ---- pass 2: emit terms ----
  double acc = 0.0;
  for (int p = begin; p < end; p += 16) {
    if (p + 16 <= ne) {
      uint4 w4 = *(const uint4*)(entries + p);
      unsigned ws[4] = {w4.x, w4.y, w4.z, w4.w};
#pragma unroll
      for (int q = 0; q < 4; ++q) {
        unsigned w = ws[q];
#pragma unroll
        for (int k = 0; k < 4; ++k) {
          unsigned b = (w >> (8 * k)) & 0xffu;
          if ((b & 0x3fu) == want) {
            ++jr;
            if (b & 64u) {
              ++tr;
              int pos = p + 4 * q + k;
              float ft = (float)tr, fj = (float)jr;
              float r_cur  = ft / g2;
              float r_prev = (ft - 1.0f) / g2;
              float p_cur  = ft / (fj + 1e-6f);
              float p_prev = (pos == 0) ? 1.0f
                                        : (ft - 1.0f) / ((fj - 1.0f) + 1e-6f);
              acc += (double)((r_cur - r_prev) * (p_cur + p_prev) * 0.5f);
            }
          }
        }
      }
    } else {
      for (int k = 0; p + k < ne && k < 16; ++k) {
        unsigned b = entries[p + k];
        if ((b & 0x3fu) == want) {
          ++jr;
          if (b & 64u) {
            ++tr;
            int pos = p + k;
            float ft = (float)tr, fj = (float)jr;
            float r_cur  = ft / g2;
            float r_prev = (ft - 1.0f) / g2;
            float p_cur  = ft / (fj + 1e-6f);
            float p_prev = (pos == 0) ? 1.0f
                                      : (ft - 1.0f) / ((fj - 1.0f) + 1e-6f);
            acc += (double)((r_cur - r_prev) * (p_cur + p_prev) * 0.5f);
          }
        }
      }
    }
  }

  // ---- block reduce ----
  for (int d = 32; d > 0; d >>= 1) acc += __shfl_down(acc, d, 64);
  if (lid == 0) wacc[wid] = acc;
  __syncthreads();
  if (tid == 0) {
    ap_out[c] = (float)(wacc[0] + wacc[1] + wacc[2] + wacc[3]);
  }
}

__global__ void k_final(const float* __restrict__ ap,
                        const int* __restrict__ gt_count,
                        float* __restrict__ out)
{
#pragma clang fp contract(off)
  if (threadIdx.x == 0 && blockIdx.x == 0) {
    float s = 0.0f, n = 0.0f;
    for (int c = 0; c < NCLS; ++c) {
      if (gt_count[c] > 0) { s += ap[c]; n += 1.0f; }
    }
    float nh = fmaxf(n, 1.0f);
    out[0] = s / nh;
  }
}

extern "C" void kernel_launch(void* const* d_in, const int* in_sizes, int n_in,
                              void* d_out, int out_size, void* d_ws, size_t ws_size,
                              hipStream_t stream) {
  const float* target = (const float*)d_in[0];
  const float* output = (const float*)d_in[1];
  int batch = in_sizes[0] / (NCELL * DDIM);
  int ne = batch * NCELL;

  uint8_t* entries = (uint8_t*)d_ws;
  size_t off = ((size_t)ne + 255) & ~(size_t)255;
  int*   gt_count = (int*)((char*)d_ws + off);
  float* ap       = (float*)((char*)d_ws + off + 64 * sizeof(int));

  (void)hipMemsetAsync(gt_count, 0, 64 * sizeof(int), stream);
  k_per_image<<<batch, 64, 0, stream>>>(target, output, entries, gt_count, batch);
  k_ap<<<NCLS, 256, 0, stream>>>(entries, gt_count, ap, ne);
  k_final<<<1, 64, 0, stream>>>(ap, gt_count, (float*)d_out);
}

// Round 5
// 225.484 us; speedup vs baseline: 1.5641x; 1.0826x over previous
//
#include <hip/hip_runtime.h>
#include <stdint.h>

#pragma clang fp contract(off)

#define NCELL 49
#define NCLS  20

struct Box { float x1, y1, x2, y2; };

__device__ __forceinline__ float sigmoid_ref(float x) {
#pragma clang fp contract(off)
  if (x >= 0.0f) {
    float z = expf(-x);
    return 1.0f / (1.0f + z);
  } else {
    float z = expf(x);
    return z / (1.0f + z);
  }
}

__device__ __forceinline__ float iou_box(Box a, Box b) {
#pragma clang fp contract(off)
  float lx = fmaxf(a.x1, b.x1);
  float ly = fmaxf(a.y1, b.y1);
  float rx = fminf(a.x2, b.x2);
  float ry = fminf(a.y2, b.y2);
  float w = fmaxf(rx - lx, 0.0f);
  float h = fmaxf(ry - ly, 0.0f);
  float inter = w * h;
  float aa = (a.x2 - a.x1) * (a.y2 - a.y1);
  float ab = (b.x2 - b.x1) * (b.y2 - b.y1);
  return inter / (aa + ab - inter);
}

__device__ __forceinline__ float permf(int dst, float v) {
  return __int_as_float(__builtin_amdgcn_ds_permute(dst << 2, __float_as_int(v)));
}

// One wave per image; 4 images per 256-thread block. No LDS, no barriers:
// all cross-lane communication via shfl / ballot / ds_permute.
__global__ __launch_bounds__(256) void k_per_image(
    const float* __restrict__ target, const float* __restrict__ output,
    uint8_t* __restrict__ entries, int* __restrict__ gt_count, int batch)
{
#pragma clang fp contract(off)
  int lane = threadIdx.x & 63;
  int img  = blockIdx.x * 4 + (threadIdx.x >> 6);
  if (img >= batch) return;            // uniform per wave
  bool a = lane < NCELL;

  // ---- per-lane direct loads: 15+15 independent float2 (8B-aligned) ----
  float tv[30], ov[30];
  if (a) {
    const float2* T2 = (const float2*)(target + (size_t)img * 1470 + lane * 30);
    const float2* O2 = (const float2*)(output + (size_t)img * 1470 + lane * 30);
#pragma unroll
    for (int i = 0; i < 15; ++i) { float2 t = T2[i]; tv[2*i] = t.x; tv[2*i+1] = t.y; }
#pragma unroll
    for (int i = 0; i < 15; ++i) { float2 o = O2[i]; ov[2*i] = o.x; ov[2*i+1] = o.y; }
  }

  float fjx = (float)(lane % 7), fiy = (float)(lane / 7);

  // ---- ground truth (raw target, no sigmoid) ----
  int gcls = 0; float gx1 = 0, gy1 = 0, gx2 = 0, gy2 = 0; bool gval = false;
  if (a) {
    float tbv = tv[10];
#pragma unroll
    for (int c = 1; c < NCLS; ++c) { float v = tv[10 + c]; if (v > tbv) { tbv = v; gcls = c; } }
    gval = tv[4] > 0.5f;
    float cx = (tv[0] + fjx) * 64.0f, cy = (tv[1] + fiy) * 64.0f;
    float w = tv[2] * 448.0f, h = tv[3] * 448.0f;
    gx1 = cx - w * 0.5f; gy1 = cy - h * 0.5f;
    gx2 = cx + w * 0.5f; gy2 = cy + h * 0.5f;
  }
  unsigned long long gvmask = __ballot(a && gval);

  // ---- gt_count via per-class ballots, one atomic per (wave,class) ----
  {
    int mycnt = 0;
#pragma unroll 1
    for (int c = 0; c < NCLS; ++c) {
      unsigned long long m = __ballot(a && gval && (gcls == c));
      if (lane == c) mycnt = (int)__popcll(m);
    }
    if (lane < NCLS && mycnt) atomicAdd(&gt_count[lane], mycnt);
  }

  // ---- predictions (sigmoid everything, identical formula) ----
  float myc = -1.0f; int myk = 0; float px1 = 0, py1 = 0, px2 = 0, py2 = 0;
  if (a) {
#pragma unroll
    for (int i = 0; i < 30; ++i) ov[i] = sigmoid_ref(ov[i]);
    float c0 = ov[4], c1 = ov[9];
    myc = fmaxf(c0, c1);
    int resp = (c1 > c0) ? 1 : 0;      // first max wins
    float x = ov[resp * 5 + 0], y = ov[resp * 5 + 1];
    float w = ov[resp * 5 + 2], h = ov[resp * 5 + 3];
    float obv = ov[10];
#pragma unroll
    for (int c = 1; c < NCLS; ++c) { float v = ov[10 + c]; if (v > obv) { obv = v; myk = c; } }
    float cx = (x + fjx) * 64.0f, cy = (y + fiy) * 64.0f;
    float W = w * 448.0f, H = h * 448.0f;
    px1 = cx - W * 0.5f; py1 = cy - H * 0.5f;
    px2 = cx + W * 0.5f; py2 = cy + H * 0.5f;
  }

  // ---- stable rank (argsort(-conf), index tiebreak) via shuffles ----
  int r = lane;
  if (a) {
    r = 0;
#pragma unroll 1
    for (int j = 0; j < NCELL; ++j) {
      float cj = __shfl(myc, j, 64);
      r += (cj > myc) || (cj == myc && j < lane);
    }
  }

  // ---- scatter to rank order: lane q ends up holding rank-q item ----
  float sx1 = permf(r, px1), sy1 = permf(r, py1);
  float sx2 = permf(r, px2), sy2 = permf(r, py2);
  float sconf = permf(r, myc);
  int   scls  = __builtin_amdgcn_ds_permute(r << 2, myk);
  Box myS; myS.x1 = sx1; myS.y1 = sy1; myS.x2 = sx2; myS.y2 = sy2;

  // ---- greedy class-aware NMS: uniform 64-bit suppression mask ----
  unsigned long long sup = 0;
#pragma unroll 1
  for (int i = 0; i < NCELL; ++i) {
    if ((sup >> i) & 1ull) continue;   // uniform branch
    int ki = __shfl(scls, i, 64);
    Box bi;
    bi.x1 = __shfl(sx1, i, 64); bi.y1 = __shfl(sy1, i, 64);
    bi.x2 = __shfl(sx2, i, 64); bi.y2 = __shfl(sy2, i, 64);
    float v = iou_box(myS, bi);
    bool s = a && (lane > i) && (scls == ki) && (v > 0.5f);
    sup |= __ballot(s);
  }

  bool vp = a && !((sup >> lane) & 1ull) && (sconf > 0.5f);

  // ---- best same-class GT per pred (first-max semantics) ----
  float mx = -1.0f; int best = 0;
#pragma unroll 1
  for (int g = 0; g < NCELL; ++g) {
    if (!((gvmask >> g) & 1ull)) continue;   // uniform branch
    int kg = __shfl(gcls, g, 64);
    Box bg;
    bg.x1 = __shfl(gx1, g, 64); bg.y1 = __shfl(gy1, g, 64);
    bg.x2 = __shfl(gx2, g, 64); bg.y2 = __shfl(gy2, g, 64);
    float v = iou_box(myS, bg);
    bool upd = a && (scls == kg) && (v > mx);
    if (upd) { mx = v; best = g; }
  }

  // ---- greedy TP assignment: uniform, computed redundantly by all lanes ----
  unsigned long long vpmask = __ballot(vp);
  unsigned long long matched = 0, hits = 0;
#pragma unroll 1
  for (int i = 0; i < NCELL; ++i) {
    if (!((vpmask >> i) & 1ull)) continue;   // uniform
    float mxi = __shfl(mx, i, 64);
    int   bi  = __shfl(best, i, 64);
    if ((mxi > 0.5f) && !((matched >> bi) & 1ull)) {
      matched |= 1ull << bi;
      hits    |= 1ull << i;
    }
  }

  if (a) {
    entries[(size_t)img * NCELL + lane] =
        (uint8_t)(scls | (vp ? 32 : 0) | (((hits >> lane) & 1ull) ? 64 : 0));
  }
}

// Exact per-byte match mask: y has every byte < 0x40, so per-byte
// (y + 0x7f) sets bit7 iff y>=1 with NO cross-byte carry (max 0xBE).
// m has 0x80 at exactly the bytes where (b & 0x3f) == want.
__device__ __forceinline__ unsigned match_mask(unsigned w, unsigned wantx4) {
  unsigned y = (w & 0x3f3f3f3fu) ^ wantx4;
  return ~(y + 0x7f7f7f7fu) & 0x80808080u;
}

// One block per class; wave-contiguous quarters with lane-interleaved 16B
// elements (coalesced). Phase A: per-wave totals. Phase B: per-tile packed
// wave scan gives exact global (j,t) ranks; SWAR byte match + sparse emit.
__global__ __launch_bounds__(256) void k_ap(
    const uint8_t* __restrict__ entries, const int* __restrict__ gt_count,
    float* __restrict__ ap_out, int ne)
{
#pragma clang fp contract(off)
  int c = blockIdx.x, tid = threadIdx.x, wid = tid >> 6, lane = tid & 63;
  float g2 = (float)gt_count[c] + 1e-6f;
  unsigned wantx4 = (32u + (unsigned)c) * 0x01010101u;

  int nel = (ne + 15) >> 4;          // 16B elements total
  int elw = (nel + 3) >> 2;          // elements per wave
  int e0 = wid * elw;
  int e1 = e0 + elw; if (e1 > nel) e1 = nel;
  int ntile = (e1 > e0) ? ((e1 - e0 + 63) >> 6) : 0;

  __shared__ unsigned long long wt[4];
  __shared__ double wacc[4];

  // ---- phase A: per-wave (valid, tp) totals ----
  unsigned mv = 0, mt = 0;
  for (int t = 0; t < ntile; ++t) {
    int e = e0 + t * 64 + lane;
    uint4 w4 = make_uint4(0, 0, 0, 0);
    if (e < e1) {
      int p = e << 4;
      if (p + 16 <= ne) {
        w4 = *(const uint4*)(entries + p);
      } else {
        unsigned ws[4] = {0, 0, 0, 0};
        for (int k = 0; k < ne - p; ++k)
          ws[k >> 2] |= ((unsigned)entries[p + k]) << (8 * (k & 3));
        w4.x = ws[0]; w4.y = ws[1]; w4.z = ws[2]; w4.w = ws[3];
      }
    }
    unsigned wsv[4] = {w4.x, w4.y, w4.z, w4.w};
#pragma unroll
    for (int q = 0; q < 4; ++q) {
      unsigned w = wsv[q];
      unsigned m = match_mask(w, wantx4);
      mv += __popc(m);
      mt += __popc(m & (w << 1));                        // tp-bit (0x40)<<1
    }
  }
  unsigned long long tot = ((unsigned long long)mv << 32) | (unsigned long long)mt;
#pragma unroll
  for (int d = 1; d < 64; d <<= 1) tot += __shfl_xor(tot, d, 64);
  if (lane == 0) wt[wid] = tot;
  __syncthreads();
  unsigned Jrun = 0, Trun = 0;
  for (int w2 = 0; w2 < wid; ++w2) {
    Jrun += (unsigned)(wt[w2] >> 32);
    Trun += (unsigned)(wt[w2] & 0xffffffffull);
  }

  // ---- phase B: emit trapezoid terms with exact running ranks ----
  double acc = 0.0;
  for (int t = 0; t < ntile; ++t) {
    int e = e0 + t * 64 + lane;
    int p = e << 4;
    uint4 w4 = make_uint4(0, 0, 0, 0);
    if (e < e1) {
      if (p + 16 <= ne) {
        w4 = *(const uint4*)(entries + p);
      } else {
        unsigned ws[4] = {0, 0, 0, 0};
        for (int k = 0; k < ne - p; ++k)
          ws[k >> 2] |= ((unsigned)entries[p + k]) << (8 * (k & 3));
        w4.x = ws[0]; w4.y = ws[1]; w4.z = ws[2]; w4.w = ws[3];
      }
    }
    unsigned wsv[4] = {w4.x, w4.y, w4.z, w4.w};
    unsigned mm[4], tm[4];
    unsigned cv = 0, ct = 0;
#pragma unroll
    for (int q = 0; q < 4; ++q) {
      unsigned w = wsv[q];
      unsigned m = match_mask(w, wantx4);
      mm[q] = m; tm[q] = m & (w << 1);
      cv += __popc(m); ct += __popc(tm[q]);
    }
    unsigned packed = (cv << 16) | ct;      // wave sums <= 1024, no overflow
    unsigned incl = packed;
#pragma unroll
    for (int d = 1; d < 64; d <<= 1) {
      unsigned n = __shfl_up(incl, d, 64);
      if (lane >= d) incl += n;
    }
    unsigned total = __shfl(incl, 63, 64);
    unsigned excl = incl - packed;
    unsigned jr = Jrun + (excl >> 16);
    unsigned tr = Trun + (excl & 0xffffu);
#pragma unroll
    for (int q = 0; q < 4; ++q) {
      unsigned m = mm[q];
      while (m) {
        unsigned bit = (unsigned)__builtin_ctz(m);
        m &= m - 1;
        ++jr;
        if (tm[q] & (1u << bit)) {
          ++tr;
          int pos = p + 4 * q + (int)(bit >> 3);
          float ft = (float)tr, fj = (float)jr;
          float r_cur  = ft / g2;
          float r_prev = (ft - 1.0f) / g2;
          float p_cur  = ft / (fj + 1e-6f);
          float p_prev = (pos == 0) ? 1.0f
                                    : (ft - 1.0f) / ((fj - 1.0f) + 1e-6f);
          acc += (double)((r_cur - r_prev) * (p_cur + p_prev) * 0.5f);
        }
      }
    }
    Jrun += (total >> 16);
    Trun += (total & 0xffffu);
  }

  for (int d = 32; d > 0; d >>= 1) acc += __shfl_down(acc, d, 64);
  if (lane == 0) wacc[wid] = acc;
  __syncthreads();
  if (tid == 0) ap_out[c] = (float)(wacc[0] + wacc[1] + wacc[2] + wacc[3]);
}

__global__ void k_final(const float* __restrict__ ap,
                        const int* __restrict__ gt_count,
                        float* __restrict__ out)
{
#pragma clang fp contract(off)
  if (threadIdx.x == 0 && blockIdx.x == 0) {
    float s = 0.0f, n = 0.0f;
    for (int c = 0; c < NCLS; ++c) {
      if (gt_count[c] > 0) { s += ap[c]; n += 1.0f; }
    }
    float nh = fmaxf(n, 1.0f);
    out[0] = s / nh;
  }
}

extern "C" void kernel_launch(void* const* d_in, const int* in_sizes, int n_in,
                              void* d_out, int out_size, void* d_ws, size_t ws_size,
                              hipStream_t stream) {
  const float* target = (const float*)d_in[0];
  const float* output = (const float*)d_in[1];
  int batch = in_sizes[0] / (NCELL * 30);
  int ne = batch * NCELL;

  uint8_t* entries = (uint8_t*)d_ws;
  size_t off = ((size_t)ne + 255) & ~(size_t)255;
  int*   gt_count = (int*)((char*)d_ws + off);
  float* ap       = (float*)((char*)d_ws + off + 64 * sizeof(int));

  (void)hipMemsetAsync(gt_count, 0, 64 * sizeof(int), stream);
  k_per_image<<<(batch + 3) / 4, 256, 0, stream>>>(target, output, entries, gt_count, batch);
  k_ap<<<NCLS, 256, 0, stream>>>(entries, gt_count, ap, ne);
  k_final<<<1, 64, 0, stream>>>(ap, gt_count, (float*)d_out);
}